// Round 1
// baseline (525.380 us; speedup 1.0000x reference)
//
#include <hip/hip_runtime.h>
#include <hip/hip_bf16.h>

#define NHEAD 8
#define IMG   3136      // 56*56
#define NWINB 2592      // 32 * 9 * 9
#define MTOT  100352    // 32*3136

typedef __attribute__((ext_vector_type(2))) _Float16 f16x2;
typedef __attribute__((ext_vector_type(4))) float    f32x4;
typedef __attribute__((ext_vector_type(8))) short    bf16x8;
typedef __attribute__((ext_vector_type(4))) short    s16x4;
typedef __attribute__((ext_vector_type(4))) int      i32x4;

#define SWZ(byteoff, r) ((byteoff) ^ (((r)&7)<<4))

__device__ __forceinline__ short f2bf(float f){
  union { float fv; unsigned u; } a; a.fv = f;
  unsigned u = a.u;
  unsigned r = (u + 0x7fffu + ((u >> 16) & 1u)) >> 16;
  return (short)r;
}

__device__ __forceinline__ float dot2f16(f16x2 a, f16x2 b, float c){
#if __has_builtin(__builtin_amdgcn_fdot2)
  return __builtin_amdgcn_fdot2(a, b, c, false);
#else
  return c + (float)a[0]*(float)b[0] + (float)a[1]*(float)b[1];
#endif
}

// ---------------- K0: weight prep ----------------
// blocks 0..63  : W1^T tiles (fc1_w 256x1024 -> w1t [1024][256] bf16)
// blocks 64..127: W2^T tiles (fc2_w 1024x256 -> w2t [256][1024] bf16)
// block 128     : spatial weight pack -> f16 j-pairs [h*49+i][25]
__global__ void prep_k(const float* __restrict__ fc1w, const float* __restrict__ fc2w,
                       const float* __restrict__ spw,
                       short* __restrict__ w1t, short* __restrict__ w2t,
                       f16x2* __restrict__ wsp)
{
  __shared__ float tl[64*65];
  int bid = blockIdx.x, t = threadIdx.x;
  if (bid < 64) {
    int kt = bid >> 4, nt = bid & 15;
    int k0 = kt*64, n0 = nt*64;
    for (int rep = 0; rep < 16; ++rep) {
      int row = rep*4 + (t>>6), col = t&63;
      tl[row*65+col] = fc1w[(size_t)(k0+row)*1024 + n0 + col];
    }
    __syncthreads();
    for (int rep = 0; rep < 16; ++rep) {
      int nr = rep*4 + (t>>6), kc = t&63;
      w1t[(size_t)(n0+nr)*256 + k0 + kc] = f2bf(tl[kc*65 + nr]);
    }
  } else if (bid < 128) {
    int id = bid - 64;
    int kt = id >> 2, nt = id & 3;
    int k0 = kt*64, n0 = nt*64;
    for (int rep = 0; rep < 16; ++rep) {
      int row = rep*4 + (t>>6), col = t&63;
      tl[row*65+col] = fc2w[(size_t)(k0+row)*256 + n0 + col];
    }
    __syncthreads();
    for (int rep = 0; rep < 16; ++rep) {
      int nr = rep*4 + (t>>6), kc = t&63;
      w2t[(size_t)(n0+nr)*1024 + k0 + kc] = f2bf(tl[kc*65 + nr]);
    }
  } else {
    for (int idx = t; idx < 9800; idx += 256) {
      int hi_ = idx/25, jp = idx - hi_*25;
      int j0 = jp*2;
      float lo = spw[hi_*49 + j0];
      float hi = (j0+1 < 49) ? spw[hi_*49 + j0 + 1] : 0.f;
      f16x2 v; v[0] = (_Float16)lo; v[1] = (_Float16)hi;
      wsp[idx] = v;
    }
  }
}

// ---------------- K1: LN1 + spatial window MLP + residual -> x1 (=d_out) ----------------
// one block per window (b, wi, wj). pad: top/left 4, bottom/right 3.
__global__ __launch_bounds__(256,2) void win_k(
    const float* __restrict__ x, const float* __restrict__ n1w, const float* __restrict__ n1b,
    const float* __restrict__ spb, const f16x2* __restrict__ wsp,
    float* __restrict__ x1)
{
  __shared__ _Float16 lx[25*256*2];   // [jp][c][2] f16, j-pairs; 25600 B
  __shared__ f16x2 lw[8*49*25];       // [h][i][jp]; 39200 B
  int t = threadIdx.x, lane = t & 63, wave = t >> 6;
  int bid = blockIdx.x;
  int b = bid/81, rem = bid - b*81, wi = rem/9, wj = rem - (rem/9)*9;

  // zero x-tile (covers padded positions + j=49 pad half)
  int* lxi = (int*)lx;
  for (int i = t; i < 6400; i += 256) lxi[i] = 0;
  // stage packed spatial weights
  for (int i = t; i < 9800; i += 256) lw[i] = wsp[i];
  __syncthreads();

  f32x4 wv = *(const f32x4*)(n1w + lane*4);
  f32x4 bv = *(const f32x4*)(n1b + lane*4);

  for (int i = wave; i < 49; i += 4) {
    int iy = i/7, ix = i - iy*7;
    int hh = wi*7 + iy - 4, ww = wj*7 + ix - 4;
    if (hh < 0 || hh >= 56 || ww < 0 || ww >= 56) continue;  // uniform per wave
    const float* row = x + ((size_t)(b*IMG + hh*56 + ww))*256;
    f32x4 v = *(const f32x4*)(row + lane*4);
    float s  = v[0]+v[1]+v[2]+v[3];
    float s2 = v[0]*v[0]+v[1]*v[1]+v[2]*v[2]+v[3]*v[3];
    #pragma unroll
    for (int m = 1; m < 64; m <<= 1) { s += __shfl_xor(s, m); s2 += __shfl_xor(s2, m); }
    float mu = s * (1.f/256.f);
    float var = s2 * (1.f/256.f) - mu*mu;
    float rs = rsqrtf(var + 1e-5f);
    int base = ((i>>1)*256 + lane*4)*2 + (i&1);
    #pragma unroll
    for (int q = 0; q < 4; ++q)
      lx[base + q*2] = (_Float16)(((v[q]-mu)*rs)*wv[q] + bv[q]);
  }
  __syncthreads();

  int c = t, h = t >> 5;
  const f16x2* wrow = lw + h*1225;    // [i][jp]
  float acc[49];
  #pragma unroll
  for (int i = 0; i < 49; ++i) acc[i] = 0.f;
  for (int jp = 0; jp < 25; ++jp) {
    f16x2 xp = *(const f16x2*)&lx[(jp*256 + c)*2];
    #pragma unroll
    for (int i = 0; i < 49; ++i)
      acc[i] = dot2f16(wrow[i*25 + jp], xp, acc[i]);
  }

  #pragma unroll
  for (int i = 0; i < 49; ++i) {
    int iy = i/7, ix = i - iy*7;
    int hh = wi*7 + iy - 4, ww = wj*7 + ix - 4;
    if (hh < 0 || hh >= 56 || ww < 0 || ww >= 56) continue;
    size_t off = ((size_t)(b*IMG + hh*56 + ww))*256 + c;
    x1[off] = x[off] + acc[i] + spb[h*49 + i];
  }
}

// ---------------- K2: fused LN2 + fc1 + GeLU + fc2 + residual (in-place on d_out) ----------------
// block: 128 rows, 512 thr (8 waves). LDS: a2[128][256]bf16 | w1s[128][64] | hc[128][128] | w2s[256][64]
__global__ __launch_bounds__(512,2) void mlp_k(
    const float* x1, float* out,
    const short* __restrict__ w1t, const short* __restrict__ w2t,
    const float* __restrict__ n2w, const float* __restrict__ n2b,
    const float* __restrict__ b1, const float* __restrict__ b2)
{
  extern __shared__ char sm[];
  char* a2  = sm;                 // 65536
  char* w1s = sm + 65536;         // 16384
  char* hcb = sm + 81920;         // 32768
  char* w2s = sm + 114688;        // 32768

  int t = threadIdx.x, lane = t & 63, wave = t >> 6;
  int m0 = blockIdx.x * 128;

  f32x4 nw = *(const f32x4*)(n2w + lane*4);
  f32x4 nb = *(const f32x4*)(n2b + lane*4);

  // Phase A: LN2 of this block's 128 rows -> a2 (bf16, swizzled)
  for (int rr = wave*16; rr < wave*16 + 16; ++rr) {
    f32x4 v = *(const f32x4*)(x1 + (size_t)(m0+rr)*256 + lane*4);
    float s  = v[0]+v[1]+v[2]+v[3];
    float s2 = v[0]*v[0]+v[1]*v[1]+v[2]*v[2]+v[3]*v[3];
    #pragma unroll
    for (int m = 1; m < 64; m <<= 1){ s += __shfl_xor(s,m); s2 += __shfl_xor(s2,m); }
    float mu = s*(1.f/256.f);
    float rs = rsqrtf(s2*(1.f/256.f) - mu*mu + 1e-5f);
    s16x4 pk;
    #pragma unroll
    for (int q = 0; q < 4; ++q) pk[q] = f2bf((v[q]-mu)*rs*nw[q] + nb[q]);
    *(s16x4*)(a2 + SWZ(rr*512 + lane*8, rr)) = pk;
  }
  __syncthreads();

  int wm = wave >> 2, wn = wave & 3;   // G1: wave -> (64-row half, 32-col quarter)
  f32x4 accO[8][2];
  #pragma unroll
  for (int i=0;i<8;++i)
    #pragma unroll
    for (int j=0;j<2;++j){ f32x4 z = {0.f,0.f,0.f,0.f}; accO[i][j] = z; }

  for (int ch = 0; ch < 8; ++ch) {
    f32x4 accH[4][2];
    #pragma unroll
    for (int i=0;i<4;++i)
      #pragma unroll
      for (int j=0;j<2;++j){ f32x4 z = {0.f,0.f,0.f,0.f}; accH[i][j] = z; }

    // ---- GEMM1: a2[128][256] @ W1t[ch*128..+128][256]^T ----
    for (int ks = 0; ks < 4; ++ks) {
      #pragma unroll
      for (int q = 0; q < 2; ++q) {               // stage w1s [128][64]
        int vi = q*512 + t;
        int row = vi >> 3, c8 = vi & 7;
        i32x4 v = *(const i32x4*)(w1t + (size_t)(ch*128 + row)*256 + ks*64 + c8*8);
        *(i32x4*)(w1s + SWZ(row*128 + c8*16, row)) = v;
      }
      __syncthreads();
      #pragma unroll
      for (int kc = 0; kc < 2; ++kc) {
        bf16x8 afr[4], bfr[2];
        int kb = ks*128 + kc*64 + (lane>>4)*16;
        #pragma unroll
        for (int mi = 0; mi < 4; ++mi) {
          int row = wm*64 + mi*16 + (lane&15);
          afr[mi] = *(const bf16x8*)(a2 + SWZ(row*512 + kb, row));
        }
        int kb2 = kc*64 + (lane>>4)*16;
        #pragma unroll
        for (int ni = 0; ni < 2; ++ni) {
          int col = wn*32 + ni*16 + (lane&15);
          bfr[ni] = *(const bf16x8*)(w1s + SWZ(col*128 + kb2, col));
        }
        #pragma unroll
        for (int mi = 0; mi < 4; ++mi)
          #pragma unroll
          for (int ni = 0; ni < 2; ++ni)
            accH[mi][ni] = __builtin_amdgcn_mfma_f32_16x16x32_bf16(afr[mi], bfr[ni], accH[mi][ni], 0,0,0);
      }
      __syncthreads();
    }

    // ---- bias + exact GeLU -> hc (bf16, swizzled) ----
    float b1v[2];
    #pragma unroll
    for (int ni = 0; ni < 2; ++ni) b1v[ni] = b1[ch*128 + wn*32 + ni*16 + (lane&15)];
    #pragma unroll
    for (int mi = 0; mi < 4; ++mi) {
      #pragma unroll
      for (int ni = 0; ni < 2; ++ni) {
        int colb = (wn*32 + ni*16 + (lane&15))*2;
        #pragma unroll
        for (int q = 0; q < 4; ++q) {
          int row = wm*64 + mi*16 + (lane>>4)*4 + q;
          float val = accH[mi][ni][q] + b1v[ni];
          float g = 0.5f*val*(1.f + erff(val*0.70710678118654752f));
          *(short*)(hcb + SWZ(row*256 + colb, row)) = f2bf(g);
        }
      }
    }
    __syncthreads();

    // ---- GEMM2: accO += hc[128][128] @ W2t[:, ch*128..+128]^T ----
    for (int ks2 = 0; ks2 < 2; ++ks2) {
      #pragma unroll
      for (int q = 0; q < 4; ++q) {               // stage w2s [256][64]
        int vi = q*512 + t;
        int row = vi >> 3, c8 = vi & 7;
        i32x4 v = *(const i32x4*)(w2t + (size_t)row*1024 + ch*128 + ks2*64 + c8*8);
        *(i32x4*)(w2s + SWZ(row*128 + c8*16, row)) = v;
      }
      __syncthreads();
      #pragma unroll
      for (int kc = 0; kc < 2; ++kc) {
        bf16x8 afr[8], bfr[2];
        int kb = ks2*128 + kc*64 + (lane>>4)*16;
        #pragma unroll
        for (int mi = 0; mi < 8; ++mi) {
          int row = mi*16 + (lane&15);
          afr[mi] = *(const bf16x8*)(hcb + SWZ(row*256 + kb, row));
        }
        int kb2 = kc*64 + (lane>>4)*16;
        #pragma unroll
        for (int ni = 0; ni < 2; ++ni) {
          int col = wave*32 + ni*16 + (lane&15);
          bfr[ni] = *(const bf16x8*)(w2s + SWZ(col*128 + kb2, col));
        }
        #pragma unroll
        for (int mi = 0; mi < 8; ++mi)
          #pragma unroll
          for (int ni = 0; ni < 2; ++ni)
            accO[mi][ni] = __builtin_amdgcn_mfma_f32_16x16x32_bf16(afr[mi], bfr[ni], accO[mi][ni], 0,0,0);
      }
      __syncthreads();
    }
  }

  // ---- epilogue: out = x1 + acc + b2 ----
  float b2v[2];
  #pragma unroll
  for (int ni = 0; ni < 2; ++ni) b2v[ni] = b2[wave*32 + ni*16 + (lane&15)];
  #pragma unroll
  for (int mi = 0; mi < 8; ++mi) {
    #pragma unroll
    for (int ni = 0; ni < 2; ++ni) {
      int col = wave*32 + ni*16 + (lane&15);
      #pragma unroll
      for (int q = 0; q < 4; ++q) {
        int row = mi*16 + (lane>>4)*4 + q;
        size_t off = (size_t)(m0 + row)*256 + col;
        out[off] = x1[off] + accO[mi][ni][q] + b2v[ni];
      }
    }
  }
}

extern "C" void kernel_launch(void* const* d_in, const int* in_sizes, int n_in,
                              void* d_out, int out_size, void* d_ws, size_t ws_size,
                              hipStream_t stream) {
  const float* x    = (const float*)d_in[0];
  const float* n1w  = (const float*)d_in[1];
  const float* n1b  = (const float*)d_in[2];
  const float* spw  = (const float*)d_in[3];
  const float* spb  = (const float*)d_in[4];
  const float* n2w  = (const float*)d_in[5];
  const float* n2b  = (const float*)d_in[6];
  const float* fc1w = (const float*)d_in[7];
  const float* fc1b = (const float*)d_in[8];
  const float* fc2w = (const float*)d_in[9];
  const float* fc2b = (const float*)d_in[10];
  float* outp = (float*)d_out;

  char* ws = (char*)d_ws;
  short* w1t = (short*)ws;                    // [1024][256] bf16 : 524288 B
  short* w2t = (short*)(ws + 524288);         // [256][1024] bf16 : 524288 B
  f16x2* wsp = (f16x2*)(ws + 1048576);        // [392][25] f16x2  : 39200 B

  prep_k<<<129, 256, 0, stream>>>(fc1w, fc2w, spw, w1t, w2t, wsp);
  win_k<<<NWINB, 256, 0, stream>>>(x, n1w, n1b, spb, wsp, outp);
  hipFuncSetAttribute(reinterpret_cast<const void*>(mlp_k),
                      hipFuncAttributeMaxDynamicSharedMemorySize, 147456);
  mlp_k<<<MTOT/128, 512, 147456, stream>>>(outp, outp, w1t, w2t, n2w, n2b, fc1b, fc2b);
}